// Round 3
// baseline (312.127 us; speedup 1.0000x reference)
//
#include <hip/hip_runtime.h>
#include <stdint.h>

typedef unsigned int u32;
typedef unsigned long long u64;

#define NTOT 21824   // 128*128 + 64*64 + 32*32 + 16*16 + 8*8
#define NBATCH 16
#define TOPN 1000
#define MAXOBJ 100
#define CAP 2048     // LDS ranking capacity
#define CAPC 8192    // global candidate buffer capacity per batch

// -------------------------------------------------------------------------
// Stage 0: zero the per-batch 2048-bin histograms (16*2048 u32)
// -------------------------------------------------------------------------
__global__ void zero_hist_kernel(u32* __restrict__ h) {
    h[blockIdx.x * 1024 + threadIdx.x] = 0;
}

// -------------------------------------------------------------------------
// Stage 1: decode + fused per-batch 11-bit key histogram.
// -------------------------------------------------------------------------
__global__ __launch_bounds__(256) void decode_kernel(
    const float* __restrict__ cls0, const float* __restrict__ cls1,
    const float* __restrict__ cls2, const float* __restrict__ cls3,
    const float* __restrict__ cls4,
    const float* __restrict__ reg0, const float* __restrict__ reg1,
    const float* __restrict__ reg2, const float* __restrict__ reg3,
    const float* __restrict__ reg4,
    const float* __restrict__ ctr0, const float* __restrict__ ctr1,
    const float* __restrict__ ctr2, const float* __restrict__ ctr3,
    const float* __restrict__ ctr4,
    u32* __restrict__ keys, int* __restrict__ clsidx, float4* __restrict__ boxes,
    u32* __restrict__ hist0)
{
    __shared__ u32 bh[2048];
    for (int i = threadIdx.x; i < 2048; i += 256) bh[i] = 0;
    __syncthreads();

    int loc = blockIdx.x * 256 + threadIdx.x;
    int b = blockIdx.y;
    u32 key = 0;
    if (loc < NTOT) {
        const float *cp, *rp, *tp;
        int li, wsh; float st;
        if (loc < 16384)      { li = loc;         wsh = 7; st = 8.f;   size_t o = (size_t)b*16384 + li; cp = cls0 + o*80; rp = reg0 + o*4; tp = ctr0 + o; }
        else if (loc < 20480) { li = loc - 16384; wsh = 6; st = 16.f;  size_t o = (size_t)b*4096  + li; cp = cls1 + o*80; rp = reg1 + o*4; tp = ctr1 + o; }
        else if (loc < 21504) { li = loc - 20480; wsh = 5; st = 32.f;  size_t o = (size_t)b*1024  + li; cp = cls2 + o*80; rp = reg2 + o*4; tp = ctr2 + o; }
        else if (loc < 21760) { li = loc - 21504; wsh = 4; st = 64.f;  size_t o = (size_t)b*256   + li; cp = cls3 + o*80; rp = reg3 + o*4; tp = ctr3 + o; }
        else                  { li = loc - 21760; wsh = 3; st = 128.f; size_t o = (size_t)b*64    + li; cp = cls4 + o*80; rp = reg4 + o*4; tp = ctr4 + o; }
        int wx = li & ((1 << wsh) - 1);
        int hy = li >> wsh;
        float px = ((float)wx + 0.5f) * st;
        float py = ((float)hy + 0.5f) * st;

        const float4* c4 = (const float4*)cp;
        float maxv = -1.0f; int arg = 0;
#pragma unroll
        for (int q = 0; q < 20; ++q) {
            float4 v = c4[q];
            if (v.x > maxv) { maxv = v.x; arg = 4*q;     }
            if (v.y > maxv) { maxv = v.y; arg = 4*q + 1; }
            if (v.z > maxv) { maxv = v.z; arg = 4*q + 2; }
            if (v.w > maxv) { maxv = v.w; arg = 4*q + 3; }
        }
        float ctr = *tp;
        float score = sqrtf(maxv * ctr);       // correctly-rounded fp32 sqrt
        float4 r = *(const float4*)rp;
        float4 bx;
        bx.x = truncf(px - r.x); bx.y = truncf(py - r.y);
        bx.z = truncf(px + r.z); bx.w = truncf(py + r.w);
        size_t o = (size_t)b * NTOT + loc;
        key = (score > 0.05f) ? (__float_as_uint(score) | 0x80000000u) : 0u;
        keys[o] = key;
        clsidx[o] = arg;
        boxes[o] = bx;
        if (key) atomicAdd(&bh[key >> 21], 1u);
    }
    __syncthreads();
    for (int i = threadIdx.x; i < 2048; i += 256) {
        u32 c = bh[i];
        if (c) atomicAdd(&hist0[b * 2048 + i], c);
    }
}

// -------------------------------------------------------------------------
// Stage 2: exact top-1000 via histogram pivot + candidate gather + ranking.
// -------------------------------------------------------------------------
__device__ __forceinline__ bool sel_pass(u32 k, int lv, int t0, int t1, int t2) {
    int a = (int)(k >> 21);
    if (a != t0) return a > t0;
    if (lv == 1) return true;
    int m = (int)((k >> 10) & 2047);
    if (m != t1) return m > t1;
    if (lv == 2) return true;
    return (int)(k & 1023) >= t2;
}

__global__ __launch_bounds__(1024) void select_kernel(
    const u32* __restrict__ keys, const u32* __restrict__ hist0,
    const int* __restrict__ clsidx, const float4* __restrict__ boxes,
    u64* __restrict__ candbuf,
    float* __restrict__ tscore, float* __restrict__ tcls, float4* __restrict__ tbox)
{
    __shared__ u32 shist[2048];
    __shared__ u64 skey[CAP];          // 16 KB
    __shared__ u32 s_wtot[16];
    __shared__ int s_tf;
    __shared__ u32 s_C, s_above, s_cnt, s_cnt2;

    int b = blockIdx.x, tid = threadIdx.x;
    int lane = tid & 63, wave = tid >> 6;
    const u32* kb = keys + (size_t)b * NTOT;
    u64* cb = candbuf + (size_t)b * CAPC;

    // ---- level 1: hierarchical suffix scan of the fused histogram ----
    u32 h0 = hist0[b * 2048 + 2 * tid];
    u32 h1 = hist0[b * 2048 + 2 * tid + 1];
    if (tid == 0) { s_tf = -1; s_cnt = 0; }
    u32 x = h0 + h1;
#pragma unroll
    for (int off = 1; off < 64; off <<= 1) {
        u32 y = __shfl_down(x, off);
        if (lane + off < 64) x += y;
    }
    if (lane == 0) s_wtot[wave] = x;
    __syncthreads();
    u32 wsuf = 0, tot = 0;
    for (int w2 = 0; w2 < 16; ++w2) { u32 v = s_wtot[w2]; tot += v; if (w2 > wave) wsuf += v; }
    u32 suf0 = x + wsuf, suf1 = suf0 - h0;
    u32 total = tot;
    u32 target = (total < TOPN) ? total : TOPN;

    if (target > 0) {
        if (suf0 >= target) atomicMax(&s_tf, 2 * tid);
        if (suf1 >= target) atomicMax(&s_tf, 2 * tid + 1);
    }
    __syncthreads();
    int t0 = s_tf;
    if (target > 0) {
        if (2 * tid == t0)     { s_C = suf0; s_above = suf0 - h0; }
        if (2 * tid + 1 == t0) { s_C = suf1; s_above = suf1 - h1; }
    }
    __syncthreads();
    u32 C = (target > 0) ? s_C : 0;
    u32 above0 = (target > 0) ? s_above : 0;

    // ---- gather candidates: all valid keys with top-11 bin >= t0 ----
    if (target > 0) {
        for (int i = tid; i < NTOT; i += 1024) {
            u32 k = kb[i];
            if (k && (int)(k >> 21) >= t0) {
                u32 pos = atomicAdd(&s_cnt, 1u);
                if (pos < CAPC) cb[pos] = ((u64)k << 32) | (u32)(~i);
            }
        }
    }
    __threadfence_block();
    __syncthreads();
    bool useCand = (C <= CAPC);

    // ---- refinement (pivot narrowing on candidates only) ----
    int lv = 1, t1 = 0, t2 = 0;
    u32 finalC = C, above1 = above0;
    if (target > 0 && C > CAP) {
        shist[2 * tid] = 0; shist[2 * tid + 1] = 0;
        if (tid == 0) s_tf = -1;
        __syncthreads();
        if (useCand) {
            for (u32 i = tid; i < C; i += 1024) {
                u64 e = cb[i]; u32 k = (u32)(e >> 32);
                if ((int)(k >> 21) == t0) atomicAdd(&shist[(k >> 10) & 2047], 1u);
            }
        } else {
            for (int i = tid; i < NTOT; i += 1024) {
                u32 k = kb[i];
                if (k && (int)(k >> 21) == t0) atomicAdd(&shist[(k >> 10) & 2047], 1u);
            }
        }
        __syncthreads();
        u32 g0 = shist[2 * tid], g1 = shist[2 * tid + 1];
        u32 need2 = target - above0;
        u32 x2 = g0 + g1;
#pragma unroll
        for (int off = 1; off < 64; off <<= 1) {
            u32 y = __shfl_down(x2, off);
            if (lane + off < 64) x2 += y;
        }
        if (lane == 0) s_wtot[wave] = x2;
        __syncthreads();
        u32 ws2 = 0;
        for (int w2 = wave + 1; w2 < 16; ++w2) ws2 += s_wtot[w2];
        u32 sa0 = x2 + ws2, sa1 = sa0 - g0;
        if (sa0 >= need2) atomicMax(&s_tf, 2 * tid);
        if (sa1 >= need2) atomicMax(&s_tf, 2 * tid + 1);
        __syncthreads();
        t1 = s_tf;
        if (2 * tid == t1)     { s_C = above0 + sa0; s_above = above0 + sa0 - g0; }
        if (2 * tid + 1 == t1) { s_C = above0 + sa1; s_above = above0 + sa1 - g1; }
        __syncthreads();
        finalC = s_C; above1 = s_above;
        lv = 2;

        if (finalC > CAP) {
            u32 need3 = target - above1;
            shist[2 * tid] = 0; shist[2 * tid + 1] = 0;
            if (tid == 0) s_tf = -1;
            __syncthreads();
            if (useCand) {
                for (u32 i = tid; i < C; i += 1024) {
                    u64 e = cb[i]; u32 k = (u32)(e >> 32);
                    if ((int)(k >> 21) == t0 && (int)((k >> 10) & 2047) == t1)
                        atomicAdd(&shist[k & 1023], 1u);
                }
            } else {
                for (int i = tid; i < NTOT; i += 1024) {
                    u32 k = kb[i];
                    if (k && (int)(k >> 21) == t0 && (int)((k >> 10) & 2047) == t1)
                        atomicAdd(&shist[k & 1023], 1u);
                }
            }
            __syncthreads();
            u32 g = shist[tid];
            u32 x3 = g;
#pragma unroll
            for (int off = 1; off < 64; off <<= 1) {
                u32 y = __shfl_down(x3, off);
                if (lane + off < 64) x3 += y;
            }
            if (lane == 0) s_wtot[wave] = x3;
            __syncthreads();
            u32 ws3 = 0;
            for (int w2 = wave + 1; w2 < 16; ++w2) ws3 += s_wtot[w2];
            u32 sb = x3 + ws3;
            if (sb >= need3) atomicMax(&s_tf, tid);
            __syncthreads();
            t2 = s_tf;
            if (tid == t2) s_C = above1 + sb;
            __syncthreads();
            finalC = s_C;
            lv = 3;
        }
    }

    // ---- compact passing candidates into LDS (if they fit) ----
    if (tid == 0) s_cnt2 = 0;
    __syncthreads();
    bool ldsRank = (finalC <= CAP);
    if (target > 0) {
        if (useCand) {
            for (u32 i = tid; i < C; i += 1024) {
                u64 e = cb[i]; u32 k = (u32)(e >> 32);
                if (sel_pass(k, lv, t0, t1, t2)) {
                    u32 p = atomicAdd(&s_cnt2, 1u);
                    if (ldsRank && p < CAP) skey[p] = e;
                }
            }
        } else {
            for (int i = tid; i < NTOT; i += 1024) {
                u32 k = kb[i];
                if (k && sel_pass(k, lv, t0, t1, t2)) {
                    u64 e = ((u64)k << 32) | (u32)(~i);
                    u32 p = atomicAdd(&s_cnt2, 1u);
                    if (ldsRank && p < CAP) skey[p] = e;
                }
            }
        }
    }
    __syncthreads();
    u32 M = s_cnt2; if (M > CAP) M = CAP;

    // ---- defaults ----
    for (int i = tid; i < TOPN; i += 1024) {
        size_t o = (size_t)b * TOPN + i;
        tscore[o] = -1.0f; tcls[o] = -1.0f;
        tbox[o] = make_float4(0.f, 0.f, 0.f, 0.f);
    }
    __syncthreads();

    // ---- rank by count + scatter ----
    if (target > 0) {
        if (ldsRank) {
            u64 e0 = (tid < (int)M) ? skey[tid] : 0ull;
            u64 e1 = (tid + 1024 < (int)M) ? skey[tid + 1024] : 0ull;
            u32 r0 = 0, r1 = 0;
#pragma unroll 4
            for (u32 j = 0; j < M; ++j) {
                u64 v = skey[j];
                r0 += (v > e0); r1 += (v > e1);
            }
            if (tid < (int)M && r0 < target) {
                u32 k = (u32)(e0 >> 32); u32 loc = ~(u32)e0;
                size_t src = (size_t)b * NTOT + loc, o = (size_t)b * TOPN + r0;
                tscore[o] = __uint_as_float(k & 0x7FFFFFFFu);
                tcls[o] = (float)clsidx[src]; tbox[o] = boxes[src];
            }
            if (tid + 1024 < (int)M && r1 < target) {
                u32 k = (u32)(e1 >> 32); u32 loc = ~(u32)e1;
                size_t src = (size_t)b * NTOT + loc, o = (size_t)b * TOPN + r1;
                tscore[o] = __uint_as_float(k & 0x7FFFFFFFu);
                tcls[o] = (float)clsidx[src]; tbox[o] = boxes[src];
            }
        } else if (useCand) {
            // slow exact fallback (massive ties) -- never hit on this input
            for (u32 i = tid; i < C; i += 1024) {
                u64 e = cb[i]; u32 k = (u32)(e >> 32);
                if (!sel_pass(k, lv, t0, t1, t2)) continue;
                u32 r = 0;
                for (u32 j = 0; j < C; ++j) {
                    u64 v = cb[j];
                    if (sel_pass((u32)(v >> 32), lv, t0, t1, t2) && v > e) r++;
                }
                if (r < target) {
                    u32 loc = ~(u32)e;
                    size_t src = (size_t)b * NTOT + loc, o = (size_t)b * TOPN + r;
                    tscore[o] = __uint_as_float(k & 0x7FFFFFFFu);
                    tcls[o] = (float)clsidx[src]; tbox[o] = boxes[src];
                }
            }
        } else {
            for (int i = tid; i < NTOT; i += 1024) {
                u32 k = kb[i];
                if (!k || !sel_pass(k, lv, t0, t1, t2)) continue;
                u64 e = ((u64)k << 32) | (u32)(~i);
                u32 r = 0;
                for (int j = 0; j < NTOT; ++j) {
                    u32 kj = kb[j];
                    if (!kj || !sel_pass(kj, lv, t0, t1, t2)) continue;
                    u64 v = ((u64)kj << 32) | (u32)(~j);
                    if (v > e) r++;
                }
                if (r < target) {
                    u32 loc = ~(u32)e;
                    size_t src = (size_t)b * NTOT + loc, o = (size_t)b * TOPN + r;
                    tscore[o] = __uint_as_float(k & 0x7FFFFFFFu);
                    tcls[o] = (float)clsidx[src]; tbox[o] = boxes[src];
                }
            }
        }
    }
}

// -------------------------------------------------------------------------
// Stage 3: suppression-bit matrix.  4 rows per 256-thread block; the 1000
// boxes staged once in LDS (4x less L2 traffic than 1 row/block).
// -------------------------------------------------------------------------
__global__ __launch_bounds__(256) void iou_kernel(
    const float4* __restrict__ tbox, u64* __restrict__ sup)
{
    __shared__ float4 sbox[TOPN];   // 16 KB
    int b = blockIdx.y;
    int tid = threadIdx.x, lane = tid & 63, wave = tid >> 6;
    const float4* tb = tbox + (size_t)b * TOPN;
    for (int i = tid; i < TOPN; i += 256) sbox[i] = tb[i];
    __syncthreads();
    int i = blockIdx.x * 4 + wave;  // 250*4 = 1000 rows
    float4 bi = sbox[i];
    float areai = fmaxf((bi.z - bi.x) * (bi.w - bi.y), 0.0001f);
    u64* row = sup + ((size_t)b * TOPN + i) * 16;
#pragma unroll
    for (int w = 0; w < 16; ++w) {
        int col = w * 64 + lane;
        bool bit = false;
        if (col < TOPN) {
            float4 bj = sbox[col];
            float areaj = fmaxf((bj.z - bj.x) * (bj.w - bj.y), 0.0001f);
            float tlx = fmaxf(bi.x, bj.x), tly = fmaxf(bi.y, bj.y);
            float brx = fminf(bi.z, bj.z), bry = fminf(bi.w, bj.w);
            float ow = fmaxf(brx - tlx, 0.f), oh = fmaxf(bry - tly, 0.f);
            float inter = ow * oh;
            float uni = fmaxf(areai + areaj - inter, 0.0001f);
            bit = (col > i) && (inter / uni >= 0.6f);
        }
        u64 m = __ballot(bit);
        if (lane == 0) row[w] = m;
    }
}

// -------------------------------------------------------------------------
// Stage 4: greedy serial scan (unchanged from round 2).
// -------------------------------------------------------------------------
#define CHROWS 128
#define NCHUNK 8

__global__ __launch_bounds__(1024) void finalize_kernel(
    const float* __restrict__ tscore, const float* __restrict__ tcls,
    const float4* __restrict__ tbox, const u64* __restrict__ sup,
    float* __restrict__ out)
{
    __shared__ u64 mat[2][CHROWS * 16];
    __shared__ u32 validsh[TOPN];
    __shared__ u64 removed_sh[16];
    __shared__ u32 scanbuf[1024];
    int b = blockIdx.x, tid = threadIdx.x;
    int wave = tid >> 6, lane = tid & 63;

    for (int i = tid; i < TOPN; i += 1024)
        validsh[i] = (tscore[(size_t)b * TOPN + i] > 0.05f) ? 1u : 0u;

    const u64* supb = sup + (size_t)b * TOPN * 16;
    for (int idx = tid; idx < CHROWS * 16; idx += 1024)
        mat[0][idx] = supb[idx];
    __syncthreads();

    u64 my = 0;
    if (wave == 0) {
#pragma unroll
        for (int w2 = 0; w2 < 16; ++w2) {
            int i = w2 * 64 + lane;
            bool v = (i < TOPN) ? (validsh[i] != 0) : false;
            u64 m = __ballot(v);
            if (lane == w2) my = ~m;
        }
    }

    for (int chunk = 0; chunk < NCHUNK; ++chunk) {
        if (wave > 0 && chunk + 1 < NCHUNK) {
            int nr = (chunk + 1 == NCHUNK - 1) ? (TOPN - (NCHUNK - 1) * CHROWS) : CHROWS;
            const u64* src = supb + (size_t)(chunk + 1) * CHROWS * 16;
            u64* dst = mat[(chunk + 1) & 1];
            for (int idx = tid - 64; idx < nr * 16; idx += 960)
                dst[idx] = src[idx];
        }
        if (wave == 0) {
            int r0 = chunk * CHROWS;
            int rows = (chunk == NCHUNK - 1) ? (TOPN - r0) : CHROWS;
            int lw = lane & 15;
            const u64* M = mat[chunk & 1];
            for (int sub = 0; sub < rows; sub += 64) {
                int w2 = (r0 + sub) >> 6;
                u64 cur = __shfl(my, w2);
                int nsub = rows - sub; if (nsub > 64) nsub = 64;
                const u64* R = M + sub * 16;
                int ngrp = nsub >> 3;
                u64 cme[8], cww[8];
#pragma unroll
                for (int g = 0; g < 8; ++g) { cme[g] = R[g*16 + lw]; cww[g] = R[g*16 + w2]; }
                for (int grp = 0; grp < ngrp; ++grp) {
                    u64 nme[8] = {0,0,0,0,0,0,0,0}, nww[8] = {0,0,0,0,0,0,0,0};
                    if (grp + 1 < ngrp) {
                        const u64* Rn = R + (grp + 1) * 128;
#pragma unroll
                        for (int g = 0; g < 8; ++g) { nme[g] = Rn[g*16 + lw]; nww[g] = Rn[g*16 + w2]; }
                    }
#pragma unroll
                    for (int g = 0; g < 8; ++g) {
                        int u = grp * 8 + g;
                        u64 bit = (cur >> u) & 1ull;
                        u64 act = bit - 1ull;
                        cur |= cww[g] & act;
                        my  |= cme[g] & act;
                    }
#pragma unroll
                    for (int g = 0; g < 8; ++g) { cme[g] = nme[g]; cww[g] = nww[g]; }
                }
            }
        }
        __syncthreads();
    }
    if (wave == 0 && lane < 16) removed_sh[lane] = my;
    __syncthreads();

    u32 keep = 0;
    if (tid < TOPN)
        keep = (validsh[tid] && !((removed_sh[tid >> 6] >> (tid & 63)) & 1ull)) ? 1u : 0u;
    scanbuf[tid] = keep;
    __syncthreads();
    for (int off = 1; off < 1024; off <<= 1) {
        u32 add = (tid >= off) ? scanbuf[tid - off] : 0;
        __syncthreads();
        scanbuf[tid] += add;
        __syncthreads();
    }
    int rank = (int)scanbuf[tid] - 1;

    float* out_s = out;
    float* out_c = out + NBATCH * MAXOBJ;
    float* out_b = out + 2 * NBATCH * MAXOBJ;
    if (tid < MAXOBJ)     { out_s[b * MAXOBJ + tid] = -1.f; out_c[b * MAXOBJ + tid] = -1.f; }
    if (tid < MAXOBJ * 4) out_b[b * MAXOBJ * 4 + tid] = 0.f;
    __syncthreads();
    if (tid < TOPN && keep && rank < MAXOBJ) {
        size_t o = (size_t)b * TOPN + tid;
        out_s[b * MAXOBJ + rank] = tscore[o];
        out_c[b * MAXOBJ + rank] = tcls[o];
        ((float4*)out_b)[b * MAXOBJ + rank] = tbox[o];
    }
}

// -------------------------------------------------------------------------
// Workspace layout (bytes), total 10,812,416 (unchanged):
//   keys    u32 [16][21824]     @ 0
//   clsidx  i32 [16][21824]     @ 1,396,736
//   boxes   f4  [16][21824]     @ 2,793,472
//   tscore  f32 [16][1000]      @ 8,380,416
//   tcls    f32 [16][1000]      @ 8,444,416
//   tbox    f4  [16][1000]      @ 8,508,416
//   sup     u64 [16][1000][16]  @ 8,764,416  (written by iou, after select)
//   candbuf u64 [16][8192]      @ 8,764,416  (overlaps sup -- dead by iou)
//   hist0   u32 [16][2048]      @ 9,812,992  (inside sup region too)
// -------------------------------------------------------------------------
extern "C" void kernel_launch(void* const* d_in, const int* in_sizes, int n_in,
                              void* d_out, int out_size, void* d_ws, size_t ws_size,
                              hipStream_t stream) {
    (void)in_sizes; (void)n_in; (void)out_size; (void)ws_size;
    const float* cls[5]; const float* reg[5]; const float* ctr[5];
    for (int l = 0; l < 5; ++l) {
        cls[l] = (const float*)d_in[4 * l + 0];
        reg[l] = (const float*)d_in[4 * l + 1];
        ctr[l] = (const float*)d_in[4 * l + 2];
    }
    char* w = (char*)d_ws;
    u32*    keys   = (u32*)(w + 0);
    int*    clsidx = (int*)(w + 1396736);
    float4* boxes  = (float4*)(w + 2793472);
    float*  tscore = (float*)(w + 8380416);
    float*  tcls   = (float*)(w + 8444416);
    float4* tbox   = (float4*)(w + 8508416);
    u64*    sup    = (u64*)(w + 8764416);
    u64*    candbuf= (u64*)(w + 8764416);
    u32*    hist0  = (u32*)(w + 9812992);

    zero_hist_kernel<<<32, 1024, 0, stream>>>(hist0);
    decode_kernel<<<dim3((NTOT + 255) / 256, NBATCH), 256, 0, stream>>>(
        cls[0], cls[1], cls[2], cls[3], cls[4],
        reg[0], reg[1], reg[2], reg[3], reg[4],
        ctr[0], ctr[1], ctr[2], ctr[3], ctr[4],
        keys, clsidx, boxes, hist0);
    select_kernel<<<NBATCH, 1024, 0, stream>>>(keys, hist0, clsidx, boxes, candbuf,
                                               tscore, tcls, tbox);
    iou_kernel<<<dim3(TOPN / 4, NBATCH), 256, 0, stream>>>(tbox, sup);
    finalize_kernel<<<NBATCH, 1024, 0, stream>>>(tscore, tcls, tbox, sup, (float*)d_out);
}